// Round 6
// baseline (114.408 us; speedup 1.0000x reference)
//
#include <hip/hip_runtime.h>
#include <hip/hip_bf16.h>

// Problem constants (fixed by reference)
#define B_    4
#define Qn_   2048
#define S_    21760   // 128*128 + 64*64 + 32*32 + 16*16

typedef short  bfx4    __attribute__((ext_vector_type(4)));
typedef short  short8  __attribute__((ext_vector_type(8)));
typedef float  floatx4 __attribute__((ext_vector_type(4)));

__device__ __forceinline__ unsigned short f2bf(float f) {
    unsigned int u = __builtin_bit_cast(unsigned int, f);
    u += 0x7fffu + ((u >> 16) & 1u);   // round-to-nearest-even
    return (unsigned short)(u >> 16);
}
__device__ __forceinline__ float bf2f(unsigned short h) {
    unsigned int u = ((unsigned int)h) << 16;
    return __builtin_bit_cast(float, u);
}

// ---------------------------------------------------------------------------
// Prep: cast+transpose weights to bf16 NxK, concat off|attn, concat biases.
// ---------------------------------------------------------------------------
__global__ __launch_bounds__(896) void prep_w(
        const float* __restrict__ Wv, const float* __restrict__ Wo,
        const float* __restrict__ Woff, const float* __restrict__ Wattn,
        const float* __restrict__ boff, const float* __restrict__ battn,
        short* __restrict__ Wvt, short* __restrict__ Wot,
        short* __restrict__ Wcat, float* __restrict__ bcat) {
    const int k = blockIdx.x;      // 0..255
    const int t = threadIdx.x;
    if (t < 256) {
        Wvt[t * 256 + k] = (short)f2bf(Wv[k * 256 + t]);
    } else if (t < 512) {
        const int n = t - 256;
        Wot[n * 256 + k] = (short)f2bf(Wo[k * 256 + n]);
    } else {
        const int n = t - 512;     // 0..383
        const float w = (n < 256) ? Woff[k * 256 + n] : Wattn[k * 128 + (n - 256)];
        Wcat[n * 256 + k] = (short)f2bf(w);
    }
    if (blockIdx.x == 0 && t < 384)
        bcat[t] = (t < 256) ? boff[t] : battn[t - 256];
}

// ---------------------------------------------------------------------------
// Full-K barrier-free GEMM: C[M x Ntot] = A[M x 256] @ B[256 x Ntot] + bias
//   Block: BM=64 rows x (WN*64) cols, WN waves; wave = 64x64 (4x4 frags).
//   A staged ONCE to LDS (bf16, 16B-chunk XOR swizzle: chunk ^= row&7),
//   single __syncthreads, then fully-unrolled K-loop (8 x BK=32):
//   B-frags straight from L2 (weights resident), A-frags ds_read, both
//   2-deep prefetched, NO barriers -> no vmcnt(0) drains.
//   MFMA operands SWAPPED: mfma(b, a, acc) computes C^T-fragment, so each
//   lane holds 4 consecutive COLUMNS of one row -> row-major vector stores.
//     D: global_row = l16 (+mf*16), global_col = lq*4 + reg (+nf*16).
// ---------------------------------------------------------------------------
template<int WN, int A_BF16, int OUT_F32>
__global__ __launch_bounds__(WN * 64) void gemm_fullk(
        const void* __restrict__ Av, const short* __restrict__ Bt,
        const float* __restrict__ bias, void* __restrict__ Cv, int Ntot) {
    constexpr int NT = WN * 64;
    __shared__ short As[64 * 256];            // 32 KB

    const int tid = threadIdx.x;
    const int lane = tid & 63, wave = tid >> 6;
    const int l16 = lane & 15, lq = lane >> 4;
    const long row0 = (long)blockIdx.x * 64;
    const int  col0 = blockIdx.y * (WN * 64) + wave * 64;

    // --- B prefetch for kk=0 (from L2; 16 full 64B lines per load) ---
    const short* bp = Bt + (long)(col0 + l16) * 256 + lq * 8;
    short8 bcur[4], bnxt[4];
#pragma unroll
    for (int nf = 0; nf < 4; ++nf) bcur[nf] = *(const short8*)(bp + nf * 4096);

    // --- A stage: full 64x256 tile -> LDS bf16, swizzled ---
    if (A_BF16) {
        for (int i = tid; i < 2048; i += NT) {
            const int r = i >> 5, c = i & 31;
            short8 v = *(const short8*)((const short*)Av + (row0 + r) * 256 + c * 8);
            *(short8*)&As[r * 256 + ((c ^ (r & 7)) << 3)] = v;
        }
    } else {
        for (int i = tid; i < 2048; i += NT) {
            const int r = i >> 5, c = i & 31;
            const float* g = (const float*)Av + (row0 + r) * 256 + c * 8;
            floatx4 f0 = *(const floatx4*)g;
            floatx4 f1 = *(const floatx4*)(g + 4);
            short8 v;
#pragma unroll
            for (int j = 0; j < 4; ++j) {
                v[j]     = (short)f2bf(f0[j]);
                v[4 + j] = (short)f2bf(f1[j]);
            }
            *(short8*)&As[r * 256 + ((c ^ (r & 7)) << 3)] = v;
        }
    }
    __syncthreads();

    floatx4 acc[4][4];
#pragma unroll
    for (int i = 0; i < 4; ++i)
#pragma unroll
        for (int j = 0; j < 4; ++j) acc[i][j] = (floatx4){0.f, 0.f, 0.f, 0.f};

    // --- A-frag prefetch for kk=0 ---
    short8 acur[4], anxt[4];
#pragma unroll
    for (int mf = 0; mf < 4; ++mf) {
        const int r = mf * 16 + l16;
        acur[mf] = *(const short8*)&As[r * 256 + ((lq ^ (r & 7)) << 3)];
    }

    // --- barrier-free K loop, fully unrolled, 2-deep prefetch ---
#pragma unroll
    for (int kk = 0; kk < 8; ++kk) {
        if (kk < 7) {
#pragma unroll
            for (int nf = 0; nf < 4; ++nf)
                bnxt[nf] = *(const short8*)(bp + nf * 4096 + (kk + 1) * 32);
#pragma unroll
            for (int mf = 0; mf < 4; ++mf) {
                const int r = mf * 16 + l16;
                anxt[mf] = *(const short8*)&As[r * 256 + ((((kk + 1) * 4 + lq) ^ (r & 7)) << 3)];
            }
        }
#pragma unroll
        for (int mf = 0; mf < 4; ++mf)
#pragma unroll
            for (int nf = 0; nf < 4; ++nf)
                acc[mf][nf] = __builtin_amdgcn_mfma_f32_16x16x32_bf16(
                    bcur[nf], acur[mf], acc[mf][nf], 0, 0, 0);   // swapped -> C^T frag
#pragma unroll
        for (int nf = 0; nf < 4; ++nf) bcur[nf] = bnxt[nf];
#pragma unroll
        for (int mf = 0; mf < 4; ++mf) acur[mf] = anxt[mf];
    }

    // --- epilogue: row-major vector stores ---
#pragma unroll
    for (int mf = 0; mf < 4; ++mf) {
        const long grow = row0 + mf * 16 + l16;
#pragma unroll
        for (int nf = 0; nf < 4; ++nf) {
            const int gcol = col0 + nf * 16 + lq * 4;
            const floatx4 bv4 = *(const floatx4*)(bias + gcol);
            const floatx4 v = acc[mf][nf] + bv4;
            if (OUT_F32) {
                *(floatx4*)((float*)Cv + grow * Ntot + gcol) = v;
            } else {
                bfx4 s;
#pragma unroll
                for (int r = 0; r < 4; ++r) s[r] = (short)f2bf(v[r]);
                *(bfx4*)((short*)Cv + grow * Ntot + gcol) = s;
            }
        }
    }
}

// ---------------------------------------------------------------------------
// Sampler: softmax + deformable bilinear gather -> wv (bf16)
// 512 threads, 16 queries per block. Grid = B * (Q/16) = 512.
// ---------------------------------------------------------------------------
__global__ __launch_bounds__(512) void sampler(
        const float* __restrict__ priors,
        const int* __restrict__ shapes, const int* __restrict__ starts,
        const float* __restrict__ offattn,   // [B*Q][384]: 256 off | 128 attn logits
        const short* __restrict__ value, short* __restrict__ wv) {
    __shared__ float oa_lds[16][384];
    __shared__ float pri_lds[16][4][2];
    __shared__ int   shp_lds[4][2];
    __shared__ int   st_lds[4];

    const int tid = threadIdx.x;
    const int b   = blockIdx.x >> 7;
    const int qt  = blockIdx.x & 127;
    const long q0 = (long)qt * 16;

    const float* src = offattn + ((long)b * Qn_ + q0) * 384;
    for (int i = tid; i < 16 * 384 / 4; i += 512)
        ((floatx4*)oa_lds)[i] = ((const floatx4*)src)[i];
    if (tid < 128) ((float*)pri_lds)[tid] = priors[((long)b * Qn_ + q0) * 8 + tid];
    if (tid < 8)  ((int*)shp_lds)[tid] = shapes[tid];
    if (tid < 4)  st_lds[tid] = starts[tid];
    __syncthreads();

    if (tid < 128) {
        const int qi = tid >> 3, h = tid & 7;
        float* a = &oa_lds[qi][256 + h * 16];
        float m = a[0];
        for (int i = 1; i < 16; ++i) m = fmaxf(m, a[i]);
        float s = 0.f;
        for (int i = 0; i < 16; ++i) { float e = expf(a[i] - m); a[i] = e; s += e; }
        const float inv = 1.f / s;
        for (int i = 0; i < 16; ++i) a[i] *= inv;
    }
    __syncthreads();

    const int pairi = tid >> 2, sub = tid & 3;
    const int qi = pairi >> 3, h = pairi & 7;
    float acc[8];
#pragma unroll
    for (int j = 0; j < 8; ++j) acc[j] = 0.f;
    const short* vbase = value + (long)b * S_ * 256 + h * 32 + sub * 8;

    for (int l = 0; l < 4; ++l) {
        const int Hl = shp_lds[l][0], Wl = shp_lds[l][1];
        const int st = st_lds[l];
        const float px = pri_lds[qi][l][0], py = pri_lds[qi][l][1];
        const float invW = 1.f / (float)Wl, invH = 1.f / (float)Hl;
        for (int p = 0; p < 4; ++p) {
            const int cb = h * 16 + l * 4 + p;
            const float ox = oa_lds[qi][cb * 2], oy = oa_lds[qi][cb * 2 + 1];
            const float lx = px + ox * invW, ly = py + oy * invH;
            const float ix = lx * (float)Wl - 0.5f, iy = ly * (float)Hl - 0.5f;
            const float x0f = floorf(ix), y0f = floorf(iy);
            const int x0 = (int)x0f, y0 = (int)y0f;
            const float fx = ix - x0f, fy = iy - y0f;
            const float awv = oa_lds[qi][256 + cb];
#pragma unroll
            for (int dy = 0; dy < 2; ++dy) {
                const int yc = y0 + dy;
                if (yc < 0 || yc >= Hl) continue;
                const float wy = dy ? fy : 1.f - fy;
#pragma unroll
                for (int dx = 0; dx < 2; ++dx) {
                    const int xc = x0 + dx;
                    if (xc < 0 || xc >= Wl) continue;
                    const float wx = dx ? fx : 1.f - fx;
                    const float w = wy * wx * awv;
                    const short8 v = *(const short8*)(vbase + ((long)st + (long)yc * Wl + xc) * 256);
#pragma unroll
                    for (int j = 0; j < 8; ++j) acc[j] += w * bf2f((unsigned short)v[j]);
                }
            }
        }
    }

    short8 ov;
#pragma unroll
    for (int j = 0; j < 8; ++j) ov[j] = (short)f2bf(acc[j]);
    *(short8*)(wv + (((long)b * Qn_ + q0 + qi) * 256 + h * 32 + sub * 8)) = ov;
}

// ---------------------------------------------------------------------------
extern "C" void kernel_launch(void* const* d_in, const int* in_sizes, int n_in,
                              void* d_out, int out_size, void* d_ws, size_t ws_size,
                              hipStream_t stream) {
    const float* in_feats = (const float*)d_in[0];
    const float* priors   = (const float*)d_in[1];
    const float* sfeats   = (const float*)d_in[2];
    const int*   shapes   = (const int*)d_in[3];
    const int*   starts   = (const int*)d_in[4];
    const float* W_off    = (const float*)d_in[5];
    const float* b_off    = (const float*)d_in[6];
    const float* W_attn   = (const float*)d_in[7];
    const float* b_attn   = (const float*)d_in[8];
    const float* W_val    = (const float*)d_in[9];
    const float* b_val    = (const float*)d_in[10];
    const float* W_out    = (const float*)d_in[11];
    const float* b_out    = (const float*)d_in[12];
    float* out = (float*)d_out;

    // Workspace: Wvt 128K | Wot 128K | Wcat 192K | value 44.56M | wv 4M (short)
    //            offattn 12.58M | bcat 1.5K (f32)
    short* Wvt     = (short*)d_ws;
    short* Wot     = Wvt + 65536;
    short* Wcat    = Wot + 65536;
    short* value   = Wcat + 98304;
    short* wv      = value + (long)B_ * S_ * 256;
    float* offattn = (float*)(wv + (long)B_ * Qn_ * 256);
    float* bcat    = offattn + (long)B_ * Qn_ * 384;

    prep_w<<<256, 896, 0, stream>>>(W_val, W_out, W_off, W_attn, b_off, b_attn,
                                    Wvt, Wot, Wcat, bcat);
    // value = sample_feats @ W_val + b_val   (87040 x 256), bf16 out
    gemm_fullk<4, 0, 0><<<dim3((B_ * S_) / 64, 1), 256, 0, stream>>>(
        (const void*)sfeats, Wvt, b_val, (void*)value, 256);
    // offattn = in_feats @ [W_off|W_attn] + bcat  (8192 x 384), f32 out
    gemm_fullk<3, 0, 1><<<dim3((B_ * Qn_) / 64, 2), 192, 0, stream>>>(
        (const void*)in_feats, Wcat, bcat, (void*)offattn, 384);
    // softmax + deformable sampling
    sampler<<<B_ * (Qn_ / 16), 512, 0, stream>>>(priors, shapes, starts,
                                                 offattn, value, wv);
    // out = wv @ W_out + b_out   (8192 x 256), f32 out
    gemm_fullk<2, 1, 1><<<dim3((B_ * Qn_) / 64, 2), 128, 0, stream>>>(
        (const void*)wv, Wot, b_out, (void*)out, 256);
}